// Round 2
// baseline (1821.444 us; speedup 1.0000x reference)
//
#include <hip/hip_runtime.h>
#include <hip/hip_bf16.h>
#include <math.h>

#define D 1024
#define BATCH 256
#define N_STEPS 28
#define NWG 256
#define PITCH 1032          // shorts per bW row: 1024 + 8 pad (breaks 2048B-stride bank conflict)
#define LDS_BYTES (32 * PITCH * 2 + 1024 * 4 + 1024 * 4)   // bW + red + cld = 74240

typedef __attribute__((ext_vector_type(8))) short short8;
typedef __attribute__((ext_vector_type(4))) float f32x4;

__device__ __forceinline__ unsigned short f32_to_bf16_rne(float f) {
    union { float f; unsigned int u; } v; v.f = f;
    unsigned int u = v.u;
    u += 0x7FFFu + ((u >> 16) & 1u);
    return (unsigned short)(u >> 16);
}

// Device-scope grid barrier. bar[0]=arrive count, bar[1]=generation.
// Safe without cooperative launch: grid=256 WGs, each <=74.3KB LDS -> 2 WGs/CU
// capacity (160KB/CU) -> all WGs resident regardless of packing.
__device__ __forceinline__ void gbar(unsigned* cnt, unsigned* gen) {
    __threadfence();                 // own stores drained to L2 (+wb/inv)
    __syncthreads();                 // all waves of this WG have fenced
    if (threadIdx.x == 0) {
        __threadfence();             // writeback whole XCD L2 (covers all waves' lines)
        unsigned g = __hip_atomic_load(gen, __ATOMIC_RELAXED, __HIP_MEMORY_SCOPE_AGENT);
        unsigned a = __hip_atomic_fetch_add(cnt, 1u, __ATOMIC_ACQ_REL, __HIP_MEMORY_SCOPE_AGENT);
        if (a == NWG - 1) {
            __hip_atomic_store(cnt, 0u, __ATOMIC_RELAXED, __HIP_MEMORY_SCOPE_AGENT);
            __hip_atomic_fetch_add(gen, 1u, __ATOMIC_RELEASE, __HIP_MEMORY_SCOPE_AGENT);
        } else {
            while (__hip_atomic_load(gen, __ATOMIC_ACQUIRE, __HIP_MEMORY_SCOPE_AGENT) == g)
                __builtin_amdgcn_s_sleep(1);
        }
    }
    __syncthreads();
    __threadfence();                 // invalidate caches -> fresh z reads
}

__global__ __launch_bounds__(256, 2) void deq_solve(
    const float* __restrict__ x, const float* __restrict__ W,
    const float* __restrict__ b, const float* __restrict__ inj,
    short* __restrict__ zA, short* __restrict__ zB,
    unsigned* __restrict__ bar, float* __restrict__ out)
{
    extern __shared__ char smem[];
    short* bW  = (short*)smem;                       // [32 cols][PITCH] bf16
    float* red = (float*)(smem + 32 * PITCH * 2);    // [1024] split-K accumulator
    float* cld = red + 1024;                         // [1024] c tile f32

    const int tid  = threadIdx.x;
    const int lane = tid & 63;
    const int w    = tid >> 6;                       // wave id 0..3 (K-split)
    const int bid  = blockIdx.x;
    const int c0   = (bid & 31) * 32;
    const int r0   = (bid >> 5) * 32;

    // ---- init phase: W col-slice -> LDS bf16; c tile -> LDS; z0 = bf16(x) ----
    {
        const int col = tid & 31;
        const int k0  = (tid >> 5) * 128;            // 8 thread-groups x 128 k
        for (int kk = 0; kk < 128; ++kk) {
            const int k = k0 + kk;
            bW[col * PITCH + k] = (short)f32_to_bf16_rne(W[k * D + c0 + col]);
        }
        #pragma unroll
        for (int s = 0; s < 4; ++s) {
            const int e = tid + s * 256;
            const int r = e >> 5, cc = e & 31;
            const int gi = (r0 + r) * D + c0 + cc;
            cld[e] = inj[gi] + b[c0 + cc];
            red[e] = 0.f;
            zA[gi] = (short)f32_to_bf16_rne(x[gi]);
        }
    }
    gbar(&bar[0], &bar[1]);

    const int lrow = lane & 15;
    const int lk   = (lane >> 4) * 8;
    const int rl   = (lane >> 4) * 4;
    const int cl   = lane & 15;

    for (int t = 0; t < N_STEPS; ++t) {
        const short* zin  = (t & 1) ? zB : zA;
        short*       zout = (t & 1) ? zA : zB;

        // A fragments: rows r0+lrow and r0+16+lrow, k = w*256 + s*32 + lk (+8)
        const short* ap = zin + (r0 + lrow) * D + w * 256 + lk;
        short8 a0[8], a1[8];
        #pragma unroll
        for (int s = 0; s < 8; ++s) {
            a0[s] = *(const short8*)(ap + s * 32);
            a1[s] = *(const short8*)(ap + 16 * D + s * 32);
        }

        const short* bp = &bW[lrow * PITCH + w * 256 + lk];
        f32x4 acc00 = {0.f,0.f,0.f,0.f}, acc01 = {0.f,0.f,0.f,0.f};
        f32x4 acc10 = {0.f,0.f,0.f,0.f}, acc11 = {0.f,0.f,0.f,0.f};
        #pragma unroll
        for (int s = 0; s < 8; ++s) {
            const short8 b0 = *(const short8*)(bp + s * 32);
            const short8 b1 = *(const short8*)(bp + 16 * PITCH + s * 32);
            acc00 = __builtin_amdgcn_mfma_f32_16x16x32_bf16(a0[s], b0, acc00, 0, 0, 0);
            acc01 = __builtin_amdgcn_mfma_f32_16x16x32_bf16(a0[s], b1, acc01, 0, 0, 0);
            acc10 = __builtin_amdgcn_mfma_f32_16x16x32_bf16(a1[s], b0, acc10, 0, 0, 0);
            acc11 = __builtin_amdgcn_mfma_f32_16x16x32_bf16(a1[s], b1, acc11, 0, 0, 0);
        }

        // split-K reduce into LDS (ds_add_f32)
        #pragma unroll
        for (int q = 0; q < 4; ++q) {
            atomicAdd(&red[(rl + q) * 32 + cl],           acc00[q]);
            atomicAdd(&red[(rl + q) * 32 + cl + 16],      acc01[q]);
            atomicAdd(&red[(rl + 16 + q) * 32 + cl],      acc10[q]);
            atomicAdd(&red[(rl + 16 + q) * 32 + cl + 16], acc11[q]);
        }
        __syncthreads();

        if (t == N_STEPS - 1) {
            #pragma unroll
            for (int s = 0; s < 4; ++s) {
                const int e = tid + s * 256;
                out[(r0 + (e >> 5)) * D + c0 + (e & 31)] = tanhf(red[e] + cld[e]);
            }
        } else {
            #pragma unroll
            for (int s = 0; s < 4; ++s) {
                const int e = tid + s * 256;
                float v = red[e];
                red[e] = 0.f;                       // re-zero for next iteration
                v = tanhf(v + cld[e]);
                zout[(r0 + (e >> 5)) * D + c0 + (e & 31)] = (short)f32_to_bf16_rne(v);
            }
            gbar(&bar[0], &bar[1]);
        }
    }
}

extern "C" void kernel_launch(void* const* d_in, const int* in_sizes, int n_in,
                              void* d_out, int out_size, void* d_ws, size_t ws_size,
                              hipStream_t stream) {
    const float* x   = (const float*)d_in[0];
    const float* W   = (const float*)d_in[1];
    const float* b   = (const float*)d_in[2];
    const float* inj = (const float*)d_in[3];
    float* out = (float*)d_out;

    char* ws = (char*)d_ws;
    short* zA = (short*)ws;                               // 512 KB bf16
    short* zB = (short*)(ws + 512 * 1024);                // 512 KB bf16
    unsigned* bar = (unsigned*)(ws + 1024 * 1024);        // 8 B barrier state

    hipMemsetAsync(bar, 0, 2 * sizeof(unsigned), stream);
    deq_solve<<<dim3(NWG), dim3(256), LDS_BYTES, stream>>>(x, W, b, inj, zA, zB, bar, out);
}

// Round 3
// 261.081 us; speedup vs baseline: 6.9765x; 6.9765x over previous
//
#include <hip/hip_runtime.h>
#include <hip/hip_bf16.h>
#include <math.h>

#define D 1024
#define NWG 256
#define N_STEPS 20
#define PITCH 1032          // shorts per bW row: 1024 + 8 pad
#define LDS_BYTES (32 * PITCH * 2 + 1024 * 4 + 1024 * 4)   // bW + red + cld = 74240

typedef __attribute__((ext_vector_type(8))) short short8;
typedef __attribute__((ext_vector_type(4))) float f32x4;

__device__ __forceinline__ unsigned short f32_to_bf16_rne(float f) {
    union { float f; unsigned int u; } v; v.f = f;
    unsigned int u = v.u;
    u += 0x7FFFu + ((u >> 16) & 1u);
    return (unsigned short)(u >> 16);
}

// LLC-coherent (agent-scope) 16B load as two 8B atomic loads: bypasses the
// (possibly stale) L1/L2 of this XCD, reads the device-coherent LLC.
__device__ __forceinline__ short8 llc_load16(const short* p) {
    union { short8 s; unsigned long long q[2]; } u;
    u.q[0] = __hip_atomic_load((unsigned long long*)p,       __ATOMIC_RELAXED, __HIP_MEMORY_SCOPE_AGENT);
    u.q[1] = __hip_atomic_load((unsigned long long*)(p + 4), __ATOMIC_RELAXED, __HIP_MEMORY_SCOPE_AGENT);
    return u.s;
}

// Agent-scope 8B store: write-through to LLC, leaves no dirty L2 lines.
__device__ __forceinline__ void llc_store8(short* p, unsigned long long v) {
    __hip_atomic_store((unsigned long long*)p, v, __ATOMIC_RELAXED, __HIP_MEMORY_SCOPE_AGENT);
}

// Grid barrier: monotone 2-level counter tree in LLC. No cache-maintenance
// instructions at all — everything communicated between WGs goes through
// agent-scope (sc1) accesses. Counters are zeroed by the captured memset at
// the start of every launch, so replays are safe.
// Safe without cooperative launch: 256 WGs x 74.3KB LDS -> >=2 WGs/CU
// capacity on 256 CUs -> all WGs resident.
__device__ __forceinline__ void gbar(unsigned* leaf, unsigned* root,
                                     unsigned target, int tid, int bid) {
    __syncthreads();   // compiler drains vmcnt before s_barrier -> z stores at LLC
    if (tid == 0) {
        unsigned a = __hip_atomic_fetch_add(&leaf[bid & 31], 1u,
                        __ATOMIC_RELAXED, __HIP_MEMORY_SCOPE_AGENT);
        if ((a & 7u) == 7u)   // last of this leaf's 8 arrivals this round
            __hip_atomic_fetch_add(root, 1u, __ATOMIC_RELAXED, __HIP_MEMORY_SCOPE_AGENT);
        while (__hip_atomic_load(root, __ATOMIC_RELAXED, __HIP_MEMORY_SCOPE_AGENT) < target)
            __builtin_amdgcn_s_sleep(4);
    }
    __syncthreads();
}

__global__ __launch_bounds__(256, 2) void deq_solve(
    const float* __restrict__ x, const float* __restrict__ W,
    const float* __restrict__ b, const float* __restrict__ inj,
    short* __restrict__ zA, short* __restrict__ zB,
    unsigned* __restrict__ bar, float* __restrict__ out)
{
    extern __shared__ char smem[];
    short* bW  = (short*)smem;                       // [32 cols][PITCH] bf16
    float* red = (float*)(smem + 32 * PITCH * 2);    // [1024] split-K accumulator
    float* cld = red + 1024;                         // [1024] c tile f32

    unsigned* leaf = bar;        // [32]
    unsigned* root = bar + 32;   // [1]

    const int tid  = threadIdx.x;
    const int lane = tid & 63;
    const int w    = tid >> 6;                       // wave id 0..3 (K-split)
    const int bid  = blockIdx.x;
    const int c0   = (bid & 31) * 32;
    const int r0   = (bid >> 5) * 32;

    // ---- init: W col-slice -> LDS bf16; c tile -> LDS; z0 = bf16(x) ----
    {
        const int col = tid & 31;
        const int k0  = (tid >> 5) * 128;
        for (int kk = 0; kk < 128; ++kk) {
            const int k = k0 + kk;
            bW[col * PITCH + k] = (short)f32_to_bf16_rne(W[k * D + c0 + col]);
        }
        #pragma unroll
        for (int s = 0; s < 4; ++s) {
            const int e = tid + s * 256;
            const int r = e >> 5, cc = e & 31;
            cld[e] = inj[(r0 + r) * D + c0 + cc] + b[c0 + cc];
            red[e] = 0.f;
        }
        // z0 tile: 4 consecutive bf16 per thread, one 8B LLC store
        const int e4 = tid * 4;
        const int r = e4 >> 5, cc = e4 & 31;
        const int gi = (r0 + r) * D + c0 + cc;
        unsigned long long v = 0;
        #pragma unroll
        for (int j = 0; j < 4; ++j)
            v |= (unsigned long long)f32_to_bf16_rne(x[gi + j]) << (16 * j);
        llc_store8(&zA[gi], v);
    }
    gbar(leaf, root, 32u, tid, bid);

    const int lrow = lane & 15;
    const int lk   = (lane >> 4) * 8;
    const int rl   = (lane >> 4) * 4;
    const int cl   = lane & 15;

    for (int t = 0; t < N_STEPS; ++t) {
        const short* zin  = (t & 1) ? zB : zA;
        short*       zout = (t & 1) ? zA : zB;

        // A fragments via LLC loads (fresh, placement-independent)
        const short* ap = zin + (r0 + lrow) * D + w * 256 + lk;
        short8 a0[8], a1[8];
        #pragma unroll
        for (int s = 0; s < 8; ++s) {
            a0[s] = llc_load16(ap + s * 32);
            a1[s] = llc_load16(ap + 16 * D + s * 32);
        }

        const short* bp = &bW[lrow * PITCH + w * 256 + lk];
        f32x4 acc00 = {0.f,0.f,0.f,0.f}, acc01 = {0.f,0.f,0.f,0.f};
        f32x4 acc10 = {0.f,0.f,0.f,0.f}, acc11 = {0.f,0.f,0.f,0.f};
        #pragma unroll
        for (int s = 0; s < 8; ++s) {
            const short8 b0 = *(const short8*)(bp + s * 32);
            const short8 b1 = *(const short8*)(bp + 16 * PITCH + s * 32);
            acc00 = __builtin_amdgcn_mfma_f32_16x16x32_bf16(a0[s], b0, acc00, 0, 0, 0);
            acc01 = __builtin_amdgcn_mfma_f32_16x16x32_bf16(a0[s], b1, acc01, 0, 0, 0);
            acc10 = __builtin_amdgcn_mfma_f32_16x16x32_bf16(a1[s], b0, acc10, 0, 0, 0);
            acc11 = __builtin_amdgcn_mfma_f32_16x16x32_bf16(a1[s], b1, acc11, 0, 0, 0);
        }

        // split-K reduce into LDS (ds_add_f32)
        #pragma unroll
        for (int q = 0; q < 4; ++q) {
            atomicAdd(&red[(rl + q) * 32 + cl],           acc00[q]);
            atomicAdd(&red[(rl + q) * 32 + cl + 16],      acc01[q]);
            atomicAdd(&red[(rl + 16 + q) * 32 + cl],      acc10[q]);
            atomicAdd(&red[(rl + 16 + q) * 32 + cl + 16], acc11[q]);
        }
        __syncthreads();

        // epilogue: 4 consecutive elements per thread (same row)
        const int e4 = tid * 4;
        const int r  = e4 >> 5, cc = e4 & 31;
        const int gi = (r0 + r) * D + c0 + cc;

        if (t == N_STEPS - 1) {
            f32x4 o;
            #pragma unroll
            for (int j = 0; j < 4; ++j)
                o[j] = tanhf(red[e4 + j] + cld[e4 + j]);
            *(f32x4*)(&out[gi]) = o;
        } else {
            unsigned long long v = 0;
            #pragma unroll
            for (int j = 0; j < 4; ++j) {
                float val = tanhf(red[e4 + j] + cld[e4 + j]);
                red[e4 + j] = 0.f;   // re-zero for next iteration
                v |= (unsigned long long)f32_to_bf16_rne(val) << (16 * j);
            }
            llc_store8(&zout[gi], v);
            gbar(leaf, root, 32u * (unsigned)(t + 2), tid, bid);
        }
    }
}

extern "C" void kernel_launch(void* const* d_in, const int* in_sizes, int n_in,
                              void* d_out, int out_size, void* d_ws, size_t ws_size,
                              hipStream_t stream) {
    const float* x   = (const float*)d_in[0];
    const float* W   = (const float*)d_in[1];
    const float* b   = (const float*)d_in[2];
    const float* inj = (const float*)d_in[3];
    float* out = (float*)d_out;

    char* ws = (char*)d_ws;
    short* zA = (short*)ws;                               // 512 KB bf16
    short* zB = (short*)(ws + 512 * 1024);                // 512 KB bf16
    unsigned* bar = (unsigned*)(ws + 1024 * 1024);        // 33 u32 counters

    hipMemsetAsync(bar, 0, 33 * sizeof(unsigned), stream);
    deq_solve<<<dim3(NWG), dim3(256), LDS_BYTES, stream>>>(x, W, b, inj, zA, zB, bar, out);
}